// Round 6
// baseline (78.267 us; speedup 1.0000x reference)
//
#include <hip/hip_runtime.h>

typedef unsigned short u16;
typedef unsigned int u32;
typedef __attribute__((ext_vector_type(8))) short short8;
typedef __attribute__((ext_vector_type(4))) float f32x4;

#define LOG_SQRT_2PI 0.9189385332046727f
#define NB 16
#define NL 512
#define NE 512
#define ZWIN 20.0f
#define MAXTB 32
#define CHUNK 4                 // K-steps of P materialized per pass
#define PPAD (CHUNK * 32 + 2)   // 130 u16 per row: (tr*130+lp)/2 -> bank tr%32, conflict-free

__device__ __forceinline__ u16 f2bf(float x) {
    u32 u = __builtin_bit_cast(u32, x);
    u += 0x7fffu + ((u >> 16) & 1u);
    return (u16)(u >> 16);
}

__device__ __forceinline__ void gload_lds16(const u16* g, u16* l) {
    __builtin_amdgcn_global_load_lds(
        (__attribute__((address_space(1))) void*)(u16*)g,
        (__attribute__((address_space(3))) void*)l,
        16, 0, 0);
}

// ---------------- K1: xc -> XcT[b][e][l] bf16 + partial dot(xc, wproj) ----------------
__global__ void k_xc(const float* __restrict__ x, const float* __restrict__ en,
                     const float* __restrict__ pt,
                     const float* __restrict__ wn, const float* __restrict__ bn,
                     const float* __restrict__ wq, const float* __restrict__ bq,
                     const float* __restrict__ wproj,
                     u16* __restrict__ XcT, float* __restrict__ dotbuf) {
    __shared__ u16 tile[64][66];
    int b = blockIdx.z;
    int l0 = blockIdx.y * 64, e0 = blockIdx.x * 64;
    int tid = threadIdx.x;         // 256
    int lr = tid >> 6, c = tid & 63;
    int e = e0 + c;
    float wn0 = wn[e * 3], wn1 = wn[e * 3 + 1], wn2 = wn[e * 3 + 2];
    float wq0 = wq[e * 3], wq1 = wq[e * 3 + 1], wq2 = wq[e * 3 + 2];
    float bias = bn[e] + bq[e];
    float wp = wproj[e];
    #pragma unroll 4
    for (int it = 0; it < 16; ++it) {
        int ll = lr * 16 + it;
        int l = l0 + ll;
        int base = b * NL;
        float em1 = (l > 0)   ? en[base + l - 1] : 0.f;
        float ev  = en[base + l];
        float ep1 = (l < 511) ? en[base + l + 1] : 0.f;
        float pm1 = (l > 0)   ? pt[base + l - 1] : 0.f;
        float pv  = pt[base + l];
        float pp1 = (l < 511) ? pt[base + l + 1] : 0.f;
        float v = x[((size_t)(base + l)) * NE + e]
                + wn0 * em1 + wn1 * ev + wn2 * ep1
                + wq0 * pm1 + wq1 * pv + wq2 * pp1 + bias;
        tile[ll][c] = f2bf(v);
        float s = v * wp;
        for (int m = 32; m; m >>= 1) s += __shfl_xor(s, m);
        if (c == 0) atomicAdd(&dotbuf[base + l], s);
    }
    __syncthreads();
    #pragma unroll 4
    for (int it = 0; it < 16; ++it) {
        int eo = lr + 4 * it;  // 0..63
        XcT[((size_t)b * NE + (e0 + eo)) * NL + l0 + c] = tile[c][eo];
    }
}

// ---------------- K2: taps(local) + cumsum means + ranges/inv_std/A + window table ----------------
__global__ void k_pre(const int* __restrict__ dint, const float* __restrict__ df,
                      const int* __restrict__ lens,
                      const float* __restrict__ wproj, const float* __restrict__ wd,
                      const float* __restrict__ bd, const float* __restrict__ bproj,
                      const float* __restrict__ dotbuf,
                      float* __restrict__ means, float* __restrict__ inv_std,
                      float* __restrict__ Aarr, int2* __restrict__ win, int ntb) {
    int b = blockIdx.x, l = threadIdx.x;  // 512 threads
    __shared__ float s[NL];
    __shared__ float red[4][8];
    __shared__ float tarr[4];
    __shared__ int slo[MAXTB], shi[MAXTB];
    // taps: each block computes its own copy (cheap)
    {
        float wp = wproj[l];
        float v[4] = {wp * wd[l * 3 + 0], wp * wd[l * 3 + 1], wp * wd[l * 3 + 2], wp * bd[l]};
        int lane = l & 63, wv = l >> 6;
        #pragma unroll
        for (int i = 0; i < 4; i++) {
            float t = v[i];
            for (int m = 32; m; m >>= 1) t += __shfl_xor(t, m);
            if (lane == 0) red[i][wv] = t;
        }
    }
    if (l < ntb) { slo[l] = NL; shi[l] = -1; }
    float d = (float)dint[b * NL + l];
    s[l] = d;
    __syncthreads();
    if (l < 4) {
        float t = 0.f;
        for (int w2 = 0; w2 < 8; w2++) t += red[l][w2];
        if (l == 3) t += bproj[0];
        tarr[l] = t;
    }
    for (int off = 1; off < NL; off <<= 1) {
        float v = (l >= off) ? s[l - off] : 0.0f;
        __syncthreads();
        s[l] += v;
        __syncthreads();
    }
    float mean = s[l] - 0.5f * d;
    means[b * NL + l] = mean;
    int base = b * NL;
    float dm1 = (l > 0)   ? df[base + l - 1] : 0.f;
    float d0  = df[base + l];
    float dp1 = (l < 511) ? df[base + l + 1] : 0.f;
    float lin = dotbuf[base + l] + tarr[3]
              + tarr[0] * dm1 + tarr[1] * d0 + tarr[2] * dp1;
    float r = (lin > 20.f) ? lin : log1pf(expf(lin));
    bool pad = (l >= lens[b]);
    if (pad) r = 1.0f;
    float sd = fmaxf(r, 0.001f);
    inv_std[base + l] = 1.0f / sd;
    Aarr[base + l] = pad ? -1e30f : (-logf(sd) - LOG_SQRT_2PI);
    if (!pad) {
        float fl = mean - ZWIN * sd - 1.0f;
        float fh = mean + ZWIN * sd + 1.0f;
        for (int tb = 0; tb < ntb; ++tb) {
            float t_lo = tb * 128.0f + 0.5f, t_hi = tb * 128.0f + 127.5f;
            if (fl <= t_hi && fh >= t_lo) {
                atomicMin(&slo[tb], l);
                atomicMax(&shi[tb], l);
            }
        }
    }
    __syncthreads();
    if (l < ntb) win[b * MAXTB + l] = make_int2(slo[l], shi[l]);
}

// ---------------- K3: per (b,tb): rn, in-band out_w rows, bf16 P-tile Pt[128][512] ----------------
__global__ __launch_bounds__(256) void k_norm(const float* __restrict__ frames,
                                              const float* __restrict__ means,
                                              const float* __restrict__ inv_std,
                                              const float* __restrict__ Aarr,
                                              const int2* __restrict__ win,
                                              float* __restrict__ wout,
                                              u16* __restrict__ Pt, int T) {
    int b = blockIdx.y, tb = blockIdx.x, t0 = tb * 128;
    int tid = threadIdx.x;  // 256
    __shared__ float4 sq[NL];
    __shared__ float fts[128], part[2][128], rvs[128];
    __shared__ u16 P[128][PPAD];
    for (int i = tid; i < NL; i += 256)
        sq[i] = make_float4(means[b * NL + i], inv_std[b * NL + i], Aarr[b * NL + i], 0.f);
    if (tid < 128) fts[tid] = (t0 + tid < T) ? frames[t0 + tid] : -1e9f;
    __syncthreads();
    int2 w = win[b * MAXTB + tb];
    if (w.x > w.y) return;  // empty band: k_gemm zero-fills everything
    int tr = tid & 127, h = tid >> 7;
    float ftr = fts[tr];
    {
        float ssum = 0.f;
        for (int l = w.x + h; l <= w.y; l += 2) {
            float4 q = sq[l];
            float z = (ftr - q.x) * q.y;
            ssum += __expf(fmaf(z, -0.5f * z, q.z));
        }
        part[h][tr] = ssum;
    }
    __syncthreads();
    if (tid < 128) rvs[tid] = 1.0f / (part[0][tid] + part[1][tid] + 1e-20f);
    __syncthreads();
    int ks0 = w.x >> 5, nst = (w.y >> 5) - ks0 + 1;
    int bl0 = ks0 * 32;
    float rv = rvs[tr];
    int tcur = t0 + tr;
    u16* PtBase = Pt + (size_t)(b * MAXTB + tb) * 128 * NL;
    for (int c0 = 0; c0 < nst; c0 += CHUNK) {
        int nc = nst - c0; if (nc > CHUNK) nc = CHUNK;
        int lb = bl0 + c0 * 32;
        for (int lp = h; lp < nc * 32; lp += 2) {
            int l = lb + lp;
            float4 q = sq[l];
            float z = (ftr - q.x) * q.y;
            float p = __expf(fmaf(z, -0.5f * z, q.z)) * rv;
            if (tcur < T) wout[((size_t)b * NL + l) * T + tcur] = p;
            P[tr][lp] = f2bf(p);
        }
        __syncthreads();
        // coalesced LDS->global copy, fixed pow2 row width (garbage cols beyond band unused)
        for (int idx = tid; idx < 128 * CHUNK * 16; idx += 256) {
            int t = idx >> 6, cc = idx & 63;  // CHUNK*16 == 64 u32/row
            int col = lb + cc * 2;
            if (col < NL) {
                u32 vv = (u32)P[t][cc * 2] | ((u32)P[t][cc * 2 + 1] << 16);
                *(u32*)&PtBase[(size_t)t * NL + col] = vv;
            }
        }
        __syncthreads();
    }
}

// ---------------- K4: pure banded GEMM (A=Pt, B=XcT) + C-write + out_w zero-fill ----------------
__global__ __launch_bounds__(256) void k_gemm(const u16* __restrict__ Pt,
                                              const u16* __restrict__ XcT,
                                              const int2* __restrict__ win,
                                              float* __restrict__ out,
                                              float* __restrict__ wout, int T) {
    __shared__ u16 At[2][128][32];
    __shared__ u16 Bt[2][128][32];
    int b = blockIdx.z;
    int t0 = blockIdx.y * 128;
    int e0 = blockIdx.x * 128;
    int tid = threadIdx.x;
    int lane = tid & 63, wid = tid >> 6;
    int wm = wid >> 1, wn = wid & 1;
    const u16* Ab = Pt + (size_t)(b * MAXTB + blockIdx.y) * 128 * NL;
    const u16* Bb = XcT + (size_t)b * NE * NL;

    int2 w = win[b * MAXTB + blockIdx.y];
    int ks0 = 0, nst = 0;
    if (w.x <= w.y) { ks0 = w.x >> 5; nst = (w.y >> 5) - ks0 + 1; }

    int srow = wid * 32 + (lane >> 2);
    int skc = (lane & 3) * 8;

    f32x4 acc[4][4];
    #pragma unroll
    for (int m = 0; m < 4; m++)
        #pragma unroll
        for (int n = 0; n < 4; n++)
            #pragma unroll
            for (int k = 0; k < 4; k++) acc[m][n][k] = 0.0f;

    auto stage = [&](int buf, int ks) {
        int l0 = ks * 32;
        const u16* ga = Ab + (size_t)srow * NL + l0 + skc;
        gload_lds16(ga, &At[buf][wid * 32][0]);
        gload_lds16(ga + 16 * NL, &At[buf][wid * 32 + 16][0]);
        const u16* gb = Bb + (size_t)(e0 + srow) * NL + l0 + skc;
        gload_lds16(gb, &Bt[buf][wid * 32][0]);
        gload_lds16(gb + 16 * NL, &Bt[buf][wid * 32 + 16][0]);
    };

    int fr = lane & 15, fk = (lane >> 4) * 8;
    if (nst > 0) {
        stage(0, ks0);
        for (int s = 0; s < nst; ++s) {
            __syncthreads();  // buf[s&1] visible; prior ds_reads drained
            if (s + 1 < nst) stage((s + 1) & 1, ks0 + s + 1);
            int buf = s & 1;
            short8 a[4], bb[4];
            #pragma unroll
            for (int m = 0; m < 4; m++)
                a[m] = *(const short8*)&At[buf][wm * 64 + m * 16 + fr][fk];
            #pragma unroll
            for (int n = 0; n < 4; n++)
                bb[n] = *(const short8*)&Bt[buf][wn * 64 + n * 16 + fr][fk];
            #pragma unroll
            for (int m = 0; m < 4; m++)
                #pragma unroll
                for (int n = 0; n < 4; n++)
                    acc[m][n] = __builtin_amdgcn_mfma_f32_16x16x32_bf16(a[m], bb[n], acc[m][n], 0, 0, 0);
        }
    }

    // --- C-write ---
    int r4 = (lane >> 4) * 4;
    #pragma unroll
    for (int m = 0; m < 4; m++) {
        int tb2 = t0 + wm * 64 + m * 16 + r4;
        #pragma unroll
        for (int j = 0; j < 4; j++) {
            int t = tb2 + j;
            if (t < T) {
                float* orow = out + ((size_t)b * T + t) * NE + e0 + wn * 64 + (lane & 15);
                #pragma unroll
                for (int n = 0; n < 4; n++) orow[n * 16] = acc[m][n][j];
            }
        }
    }

    // --- out_w zero-fill: rows [e0,e0+128) outside the K-step band (in-band done by k_norm) ---
    if (t0 < T) {
        int tcnt = T - t0; if (tcnt > 128) tcnt = 128;
        int rbeg = e0, rend = e0 + 128;
        int bl0 = ks0 * 32, bl1 = (ks0 + nst) * 32;
        int ib0 = bl0 > rbeg ? bl0 : rbeg;
        int ib1 = bl1 < rend ? bl1 : rend;
        int t4 = (tid & 31) * 4, rsub = tid >> 5;  // 8 rows per pass, float4 across t
        bool t4full = (t4 + 4 <= tcnt);
        float4 z4 = make_float4(0.f, 0.f, 0.f, 0.f);
        auto zfill = [&](int r0, int r1) {
            for (int l = r0 + rsub; l < r1; l += 8) {
                float* d = wout + ((size_t)b * NL + l) * T + t0 + t4;
                if (t4full) *(float4*)d = z4;
                else { for (int u = 0; u < 4 && t4 + u < tcnt; ++u) d[u] = 0.f; }
            }
        };
        if (ib0 >= ib1) {
            zfill(rbeg, rend);
        } else {
            zfill(rbeg, ib0);
            zfill(ib1, rend);
        }
    }
}

extern "C" void kernel_launch(void* const* d_in, const int* in_sizes, int n_in,
                              void* d_out, int out_size, void* d_ws, size_t ws_size,
                              hipStream_t stream) {
    const float* x      = (const float*)d_in[0];
    const float* df     = (const float*)d_in[1];
    const int*   dint   = (const int*)d_in[2];
    const float* en     = (const float*)d_in[3];
    const float* pt     = (const float*)d_in[4];
    const int*   lens   = (const int*)d_in[5];
    const float* frames = (const float*)d_in[6];
    const float* wd     = (const float*)d_in[7];
    const float* bd     = (const float*)d_in[8];
    const float* wn     = (const float*)d_in[9];
    const float* bn     = (const float*)d_in[10];
    const float* wq     = (const float*)d_in[11];
    const float* bq     = (const float*)d_in[12];
    const float* wproj  = (const float*)d_in[13];
    const float* bproj  = (const float*)d_in[14];

    int T = in_sizes[6];
    int ntb = (T + 127) / 128;   // <= 32

    char* ws = (char*)d_ws;
    float* means   = (float*)(ws);             // B*L
    float* inv_std = (float*)(ws + 32768);     // B*L
    float* Aarr    = (float*)(ws + 65536);     // B*L
    float* dotbuf  = (float*)(ws + 98304);     // B*L
    int2*  win     = (int2*)(ws + 131072);     // B*MAXTB
    u16*   XcT     = (u16*)(ws + 135168);      // B*E*L bf16 = 8.39 MB
    u16*   Pt      = (u16*)(ws + 8523776);     // B*MAXTB*128*512 bf16 = 67 MB

    float* out_up = (float*)d_out;                 // (B,T,E)
    float* out_w  = out_up + (size_t)NB * T * NE;  // (B,L,T)

    hipMemsetAsync(dotbuf, 0, NB * NL * sizeof(float), stream);
    k_xc<<<dim3(8, 8, NB), dim3(256), 0, stream>>>(x, en, pt, wn, bn, wq, bq, wproj,
                                                   XcT, dotbuf);
    k_pre<<<dim3(NB), dim3(512), 0, stream>>>(dint, df, lens, wproj, wd, bd, bproj,
                                              dotbuf, means, inv_std, Aarr, win, ntb);
    k_norm<<<dim3(ntb, NB), dim3(256), 0, stream>>>(frames, means, inv_std, Aarr, win,
                                                    out_w, Pt, T);
    k_gemm<<<dim3(4, ntb, NB), dim3(256), 0, stream>>>(Pt, XcT, win, out_up, out_w, T);
}

// Round 7
// 69.991 us; speedup vs baseline: 1.1182x; 1.1182x over previous
//
#include <hip/hip_runtime.h>

typedef unsigned short u16;
typedef unsigned int u32;
typedef __attribute__((ext_vector_type(8))) short short8;
typedef __attribute__((ext_vector_type(4))) float f32x4;

#define LOG_SQRT_2PI 0.9189385332046727f
#define NB 16
#define NL 512
#define NE 512
#define ZWIN 20.0f
#define MAXTB 32

__device__ __forceinline__ u16 f2bf(float x) {
    u32 u = __builtin_bit_cast(u32, x);
    u += 0x7fffu + ((u >> 16) & 1u);
    return (u16)(u >> 16);
}

__device__ __forceinline__ void gload_lds16(const u16* g, u16* l) {
    __builtin_amdgcn_global_load_lds(
        (__attribute__((address_space(1))) void*)(u16*)g,
        (__attribute__((address_space(3))) void*)l,
        16, 0, 0);
}

// ---------------- K1: xc -> XcT[b][e][l] bf16 + partial dot(xc, wproj) ----------------
__global__ void k_xc(const float* __restrict__ x, const float* __restrict__ en,
                     const float* __restrict__ pt,
                     const float* __restrict__ wn, const float* __restrict__ bn,
                     const float* __restrict__ wq, const float* __restrict__ bq,
                     const float* __restrict__ wproj,
                     u16* __restrict__ XcT, float* __restrict__ dotbuf) {
    __shared__ u16 tile[64][66];
    int b = blockIdx.z;
    int l0 = blockIdx.y * 64, e0 = blockIdx.x * 64;
    int tid = threadIdx.x;         // 256
    int lr = tid >> 6, c = tid & 63;
    int e = e0 + c;
    float wn0 = wn[e * 3], wn1 = wn[e * 3 + 1], wn2 = wn[e * 3 + 2];
    float wq0 = wq[e * 3], wq1 = wq[e * 3 + 1], wq2 = wq[e * 3 + 2];
    float bias = bn[e] + bq[e];
    float wp = wproj[e];
    #pragma unroll 4
    for (int it = 0; it < 16; ++it) {
        int ll = lr * 16 + it;
        int l = l0 + ll;
        int base = b * NL;
        float em1 = (l > 0)   ? en[base + l - 1] : 0.f;
        float ev  = en[base + l];
        float ep1 = (l < 511) ? en[base + l + 1] : 0.f;
        float pm1 = (l > 0)   ? pt[base + l - 1] : 0.f;
        float pv  = pt[base + l];
        float pp1 = (l < 511) ? pt[base + l + 1] : 0.f;
        float v = x[((size_t)(base + l)) * NE + e]
                + wn0 * em1 + wn1 * ev + wn2 * ep1
                + wq0 * pm1 + wq1 * pv + wq2 * pp1 + bias;
        tile[ll][c] = f2bf(v);
        float s = v * wp;
        for (int m = 32; m; m >>= 1) s += __shfl_xor(s, m);
        if (c == 0) atomicAdd(&dotbuf[base + l], s);
    }
    __syncthreads();
    #pragma unroll 4
    for (int it = 0; it < 16; ++it) {
        int eo = lr + 4 * it;  // 0..63
        XcT[((size_t)b * NE + (e0 + eo)) * NL + l0 + c] = tile[c][eo];
    }
}

// ---------------- K2: taps(local) + cumsum means + ranges/inv_std/A + window table ----------------
__global__ void k_pre(const int* __restrict__ dint, const float* __restrict__ df,
                      const int* __restrict__ lens,
                      const float* __restrict__ wproj, const float* __restrict__ wd,
                      const float* __restrict__ bd, const float* __restrict__ bproj,
                      const float* __restrict__ dotbuf,
                      float* __restrict__ means, float* __restrict__ inv_std,
                      float* __restrict__ Aarr, int2* __restrict__ win, int ntb) {
    int b = blockIdx.x, l = threadIdx.x;  // 512 threads
    __shared__ float s[NL];
    __shared__ float red[4][8];
    __shared__ float tarr[4];
    __shared__ int slo[MAXTB], shi[MAXTB];
    {
        float wp = wproj[l];
        float v[4] = {wp * wd[l * 3 + 0], wp * wd[l * 3 + 1], wp * wd[l * 3 + 2], wp * bd[l]};
        int lane = l & 63, wv = l >> 6;
        #pragma unroll
        for (int i = 0; i < 4; i++) {
            float t = v[i];
            for (int m = 32; m; m >>= 1) t += __shfl_xor(t, m);
            if (lane == 0) red[i][wv] = t;
        }
    }
    if (l < ntb) { slo[l] = NL; shi[l] = -1; }
    float d = (float)dint[b * NL + l];
    s[l] = d;
    __syncthreads();
    if (l < 4) {
        float t = 0.f;
        for (int w2 = 0; w2 < 8; w2++) t += red[l][w2];
        if (l == 3) t += bproj[0];
        tarr[l] = t;
    }
    for (int off = 1; off < NL; off <<= 1) {
        float v = (l >= off) ? s[l - off] : 0.0f;
        __syncthreads();
        s[l] += v;
        __syncthreads();
    }
    float mean = s[l] - 0.5f * d;
    means[b * NL + l] = mean;
    int base = b * NL;
    float dm1 = (l > 0)   ? df[base + l - 1] : 0.f;
    float d0  = df[base + l];
    float dp1 = (l < 511) ? df[base + l + 1] : 0.f;
    float lin = dotbuf[base + l] + tarr[3]
              + tarr[0] * dm1 + tarr[1] * d0 + tarr[2] * dp1;
    float r = (lin > 20.f) ? lin : log1pf(expf(lin));
    bool pad = (l >= lens[b]);
    if (pad) r = 1.0f;
    float sd = fmaxf(r, 0.001f);
    inv_std[base + l] = 1.0f / sd;
    Aarr[base + l] = pad ? -1e30f : (-logf(sd) - LOG_SQRT_2PI);
    if (!pad) {
        float fl = mean - ZWIN * sd - 1.0f;
        float fh = mean + ZWIN * sd + 1.0f;
        for (int tb = 0; tb < ntb; ++tb) {
            float t_lo = tb * 128.0f + 0.5f, t_hi = tb * 128.0f + 127.5f;
            if (fl <= t_hi && fh >= t_lo) {
                atomicMin(&slo[tb], l);
                atomicMax(&shi[tb], l);
            }
        }
    }
    __syncthreads();
    if (l < ntb) win[b * MAXTB + l] = make_int2(slo[l], shi[l]);
}

// ---------------- K3: rn[b,t] = 1/(sum_band p + eps) ----------------
__global__ __launch_bounds__(256) void k_rn(const float* __restrict__ frames,
                                            const float* __restrict__ means,
                                            const float* __restrict__ inv_std,
                                            const float* __restrict__ Aarr,
                                            const int2* __restrict__ win,
                                            float* __restrict__ rn, int T, int Tpad) {
    int b = blockIdx.y, tb = blockIdx.x, t0 = tb * 128;
    int tid = threadIdx.x;  // 256
    __shared__ float4 sq[NL];
    __shared__ float part[2][128];
    for (int i = tid; i < NL; i += 256)
        sq[i] = make_float4(means[b * NL + i], inv_std[b * NL + i], Aarr[b * NL + i], 0.f);
    __syncthreads();
    int2 w = win[b * MAXTB + tb];
    int tr = tid & 127, h = tid >> 7;
    int t = t0 + tr;
    float ft = (t < T) ? frames[t] : -1e9f;
    float s0 = 0.f, s1 = 0.f;
    int l = w.x + h;
    for (; l + 1 <= w.y; l += 4) {
        float4 q0 = sq[l], q1 = sq[l + 2];
        float z0 = (ft - q0.x) * q0.y;
        s0 += __expf(fmaf(z0, -0.5f * z0, q0.z));
        float z1 = (ft - q1.x) * q1.y;
        s1 += __expf(fmaf(z1, -0.5f * z1, q1.z));
    }
    if (l <= w.y) {
        float4 q = sq[l];
        float z = (ft - q.x) * q.y;
        s0 += __expf(fmaf(z, -0.5f * z, q.z));
    }
    part[h][tr] = s0 + s1;
    __syncthreads();
    if (tid < 128) {
        float tot = part[0][tid] + part[1][tid] + 1e-20f;
        rn[b * Tpad + t0 + tid] = 1.0f / tot;
    }
}

// ---------------- K4: banded GEMM; A-tile exps in-kernel; out_w rows split across e-blocks ----------------
__global__ __launch_bounds__(256) void k_gemm(const u16* __restrict__ XcT,
                                              const float* __restrict__ frames,
                                              const float* __restrict__ rn,
                                              const float* __restrict__ means,
                                              const float* __restrict__ inv_std,
                                              const float* __restrict__ Aarr,
                                              const int2* __restrict__ win,
                                              float* __restrict__ out,
                                              float* __restrict__ wout, int T, int Tpad) {
    __shared__ float4 sq[NL];
    __shared__ float fts[128];
    __shared__ float rvs[128];
    __shared__ u16 At[2][128][32];
    __shared__ u16 Bt[2][128][32];
    int b = blockIdx.z;
    int t0 = blockIdx.y * 128;
    int e0 = blockIdx.x * 128;
    int tid = threadIdx.x;
    int lane = tid & 63, wid = tid >> 6;
    int wm = wid >> 1, wn = wid & 1;
    const u16* Bb = XcT + (size_t)b * NE * NL;

    for (int i = tid; i < NL; i += 256)
        sq[i] = make_float4(means[b * NL + i], inv_std[b * NL + i], Aarr[b * NL + i], 0.f);
    if (tid < 128) {
        fts[tid] = (t0 + tid < T) ? frames[t0 + tid] : -1e9f;
        rvs[tid] = rn[b * Tpad + t0 + tid];
    }

    int2 w = win[b * MAXTB + blockIdx.y];
    int ks0 = 0, nst = 0;
    if (w.x <= w.y) { ks0 = w.x >> 5; nst = (w.y >> 5) - ks0 + 1; }

    __syncthreads();  // sq, fts, rvs ready

    int ta = tid >> 1;        // A-row (t offset) this thread fills
    int ha = (tid & 1) * 16;  // which 16-col half
    float ft = fts[ta];
    float rv = rvs[ta];

    int srow = wid * 32 + (lane >> 2);
    int skc = (lane & 3) * 8;

    f32x4 acc[4][4];
    #pragma unroll
    for (int m = 0; m < 4; m++)
        #pragma unroll
        for (int n = 0; n < 4; n++)
            #pragma unroll
            for (int k = 0; k < 4; k++) acc[m][n][k] = 0.0f;

    auto stage = [&](int buf, int ks) {
        int l0 = ks * 32;
        const u16* gb = Bb + (size_t)(e0 + srow) * NL + l0 + skc;
        gload_lds16(gb, &Bt[buf][wid * 32][0]);
        gload_lds16(gb + 16 * NL, &Bt[buf][wid * 32 + 16][0]);
        u32 pk[8];
        #pragma unroll
        for (int jj = 0; jj < 8; ++jj) {
            float4 q0 = sq[l0 + ha + jj * 2];
            float4 q1 = sq[l0 + ha + jj * 2 + 1];
            float z0 = (ft - q0.x) * q0.y;
            float p0 = __expf(fmaf(z0, -0.5f * z0, q0.z)) * rv;
            float z1 = (ft - q1.x) * q1.y;
            float p1 = __expf(fmaf(z1, -0.5f * z1, q1.z)) * rv;
            pk[jj] = (u32)f2bf(p0) | ((u32)f2bf(p1) << 16);
        }
        *(uint4*)&At[buf][ta][ha]     = make_uint4(pk[0], pk[1], pk[2], pk[3]);
        *(uint4*)&At[buf][ta][ha + 8] = make_uint4(pk[4], pk[5], pk[6], pk[7]);
    };

    int fr = lane & 15, fk = (lane >> 4) * 8;
    if (nst > 0) {
        stage(0, ks0);
        for (int s = 0; s < nst; ++s) {
            __syncthreads();  // buf[s&1] (ds_writes + gload_lds) visible
            if (s + 1 < nst) stage((s + 1) & 1, ks0 + s + 1);
            int buf = s & 1;
            short8 a[4], bb[4];
            #pragma unroll
            for (int m = 0; m < 4; m++)
                a[m] = *(const short8*)&At[buf][wm * 64 + m * 16 + fr][fk];
            #pragma unroll
            for (int n = 0; n < 4; n++)
                bb[n] = *(const short8*)&Bt[buf][wn * 64 + n * 16 + fr][fk];
            #pragma unroll
            for (int m = 0; m < 4; m++)
                #pragma unroll
                for (int n = 0; n < 4; n++)
                    acc[m][n] = __builtin_amdgcn_mfma_f32_16x16x32_bf16(a[m], bb[n], acc[m][n], 0, 0, 0);
        }
    }

    // --- C-write ---
    int r4 = (lane >> 4) * 4;
    #pragma unroll
    for (int m = 0; m < 4; m++) {
        int tb2 = t0 + wm * 64 + m * 16 + r4;
        #pragma unroll
        for (int j = 0; j < 4; j++) {
            int t = tb2 + j;
            if (t < T) {
                float* orow = out + ((size_t)b * T + t) * NE + e0 + wn * 64 + (lane & 15);
                #pragma unroll
                for (int n = 0; n < 4; n++) orow[n * 16] = acc[m][n][j];
            }
        }
    }

    // --- out_w epilogue: this e-block writes rows [e0, e0+128), lane <-> t coalesced ---
    if (t0 < T) {
        int tcnt = T - t0; if (tcnt > 128) tcnt = 128;
        int rbeg = e0, rend = e0 + 128;
        int bl0 = ks0 * 32, bl1 = (ks0 + nst) * 32;   // K-step-aligned band [bl0, bl1)
        int ib0 = bl0 > rbeg ? bl0 : rbeg;
        int ib1 = bl1 < rend ? bl1 : rend;
        int t4 = (tid & 31) * 4, rsub = tid >> 5;     // 8 rows per pass
        bool t4full = (t4 + 4 <= tcnt);
        float4 z4 = make_float4(0.f, 0.f, 0.f, 0.f);
        auto zfill = [&](int r0, int r1) {
            for (int l = r0 + rsub; l < r1; l += 8) {
                float* d = wout + ((size_t)b * NL + l) * T + t0 + t4;
                if (t4full) *(float4*)d = z4;
                else { for (int u = 0; u < 4 && t4 + u < tcnt; ++u) d[u] = 0.f; }
            }
        };
        if (ib0 >= ib1) {
            zfill(rbeg, rend);
        } else {
            zfill(rbeg, ib0);
            zfill(ib1, rend);
            int tt = tid & 127, half = tid >> 7;
            if (tt < tcnt) {
                float ftl = fts[tt], rvl = rvs[tt];
                float* dstc = wout + (size_t)b * NL * T + t0 + tt;
                for (int l = ib0 + half; l < ib1; l += 2) {
                    float4 q = sq[l];
                    float z = (ftl - q.x) * q.y;
                    dstc[(size_t)l * T] = __expf(fmaf(z, -0.5f * z, q.z)) * rvl;
                }
            }
        }
    }
}

extern "C" void kernel_launch(void* const* d_in, const int* in_sizes, int n_in,
                              void* d_out, int out_size, void* d_ws, size_t ws_size,
                              hipStream_t stream) {
    const float* x      = (const float*)d_in[0];
    const float* df     = (const float*)d_in[1];
    const int*   dint   = (const int*)d_in[2];
    const float* en     = (const float*)d_in[3];
    const float* pt     = (const float*)d_in[4];
    const int*   lens   = (const int*)d_in[5];
    const float* frames = (const float*)d_in[6];
    const float* wd     = (const float*)d_in[7];
    const float* bd     = (const float*)d_in[8];
    const float* wn     = (const float*)d_in[9];
    const float* bn     = (const float*)d_in[10];
    const float* wq     = (const float*)d_in[11];
    const float* bq     = (const float*)d_in[12];
    const float* wproj  = (const float*)d_in[13];
    const float* bproj  = (const float*)d_in[14];

    int T = in_sizes[6];
    int ntb = (T + 127) / 128;   // <= 32
    int Tpad = ntb * 128;

    char* ws = (char*)d_ws;
    float* means   = (float*)(ws);             // B*L
    float* inv_std = (float*)(ws + 32768);     // B*L
    float* Aarr    = (float*)(ws + 65536);     // B*L
    float* dotbuf  = (float*)(ws + 98304);     // B*L
    int2*  win     = (int2*)(ws + 131072);     // B*MAXTB
    float* rn      = (float*)(ws + 135168);    // B*Tpad (<= 256 KB)
    u16*   XcT     = (u16*)(ws + 397312);      // B*E*L bf16 = 8.39 MB

    float* out_up = (float*)d_out;                 // (B,T,E)
    float* out_w  = out_up + (size_t)NB * T * NE;  // (B,L,T)

    hipMemsetAsync(dotbuf, 0, NB * NL * sizeof(float), stream);
    k_xc<<<dim3(8, 8, NB), dim3(256), 0, stream>>>(x, en, pt, wn, bn, wq, bq, wproj,
                                                   XcT, dotbuf);
    k_pre<<<dim3(NB), dim3(512), 0, stream>>>(dint, df, lens, wproj, wd, bd, bproj,
                                              dotbuf, means, inv_std, Aarr, win, ntb);
    k_rn<<<dim3(ntb, NB), dim3(256), 0, stream>>>(frames, means, inv_std, Aarr, win,
                                                  rn, T, Tpad);
    k_gemm<<<dim3(4, ntb, NB), dim3(256), 0, stream>>>(XcT, frames, rn, means, inv_std,
                                                       Aarr, win, out_up, out_w, T, Tpad);
}

// Round 8
// 61.354 us; speedup vs baseline: 1.2757x; 1.1408x over previous
//
#include <hip/hip_runtime.h>

typedef unsigned short u16;
typedef unsigned int u32;
typedef __attribute__((ext_vector_type(8))) short short8;
typedef __attribute__((ext_vector_type(4))) float f32x4;

#define LOG_SQRT_2PI 0.9189385332046727f
#define NB 16
#define NL 512
#define NE 512
#define ZWIN 20.0f
#define MAXTB 32

__device__ __forceinline__ u16 f2bf(float x) {
    u32 u = __builtin_bit_cast(u32, x);
    u += 0x7fffu + ((u >> 16) & 1u);
    return (u16)(u >> 16);
}

__device__ __forceinline__ void gload_lds16(const u16* g, u16* l) {
    __builtin_amdgcn_global_load_lds(
        (__attribute__((address_space(1))) void*)(u16*)g,
        (__attribute__((address_space(3))) void*)l,
        16, 0, 0);
}

// ---------------- K1: xc -> XcT[b][e][l] bf16 + per-eblock partial dot(xc, wproj) ----------------
__global__ void k_xc(const float* __restrict__ x, const float* __restrict__ en,
                     const float* __restrict__ pt,
                     const float* __restrict__ wn, const float* __restrict__ bn,
                     const float* __restrict__ wq, const float* __restrict__ bq,
                     const float* __restrict__ wproj,
                     u16* __restrict__ XcT, float* __restrict__ dot8) {
    __shared__ u16 tile[64][66];
    int b = blockIdx.z;
    int l0 = blockIdx.y * 64, e0 = blockIdx.x * 64;
    int tid = threadIdx.x;         // 256
    int lr = tid >> 6, c = tid & 63;
    int e = e0 + c;
    float wn0 = wn[e * 3], wn1 = wn[e * 3 + 1], wn2 = wn[e * 3 + 2];
    float wq0 = wq[e * 3], wq1 = wq[e * 3 + 1], wq2 = wq[e * 3 + 2];
    float bias = bn[e] + bq[e];
    float wp = wproj[e];
    #pragma unroll 4
    for (int it = 0; it < 16; ++it) {
        int ll = lr * 16 + it;
        int l = l0 + ll;
        int base = b * NL;
        float em1 = (l > 0)   ? en[base + l - 1] : 0.f;
        float ev  = en[base + l];
        float ep1 = (l < 511) ? en[base + l + 1] : 0.f;
        float pm1 = (l > 0)   ? pt[base + l - 1] : 0.f;
        float pv  = pt[base + l];
        float pp1 = (l < 511) ? pt[base + l + 1] : 0.f;
        float v = x[((size_t)(base + l)) * NE + e]
                + wn0 * em1 + wn1 * ev + wn2 * ep1
                + wq0 * pm1 + wq1 * pv + wq2 * pp1 + bias;
        tile[ll][c] = f2bf(v);
        float s = v * wp;
        for (int m = 32; m; m >>= 1) s += __shfl_xor(s, m);
        if (c == 0) dot8[((size_t)(base + l)) * 8 + blockIdx.x] = s;
    }
    __syncthreads();
    #pragma unroll 4
    for (int it = 0; it < 16; ++it) {
        int eo = lr + 4 * it;  // 0..63
        XcT[((size_t)b * NE + (e0 + eo)) * NL + l0 + c] = tile[c][eo];
    }
}

// ---------------- K2: taps(local) + cumsum means + ranges/inv_std/A + window table ----------------
__global__ void k_pre(const int* __restrict__ dint, const float* __restrict__ df,
                      const int* __restrict__ lens,
                      const float* __restrict__ wproj, const float* __restrict__ wd,
                      const float* __restrict__ bd, const float* __restrict__ bproj,
                      const float* __restrict__ dot8,
                      float* __restrict__ means, float* __restrict__ inv_std,
                      float* __restrict__ Aarr, int2* __restrict__ win, int ntb) {
    int b = blockIdx.x, l = threadIdx.x;  // 512 threads
    __shared__ float s[NL];
    __shared__ float red[4][8];
    __shared__ float tarr[4];
    __shared__ int slo[MAXTB], shi[MAXTB];
    {
        float wp = wproj[l];
        float v[4] = {wp * wd[l * 3 + 0], wp * wd[l * 3 + 1], wp * wd[l * 3 + 2], wp * bd[l]};
        int lane = l & 63, wv = l >> 6;
        #pragma unroll
        for (int i = 0; i < 4; i++) {
            float t = v[i];
            for (int m = 32; m; m >>= 1) t += __shfl_xor(t, m);
            if (lane == 0) red[i][wv] = t;
        }
    }
    if (l < ntb) { slo[l] = NL; shi[l] = -1; }
    float d = (float)dint[b * NL + l];
    s[l] = d;
    __syncthreads();
    if (l < 4) {
        float t = 0.f;
        for (int w2 = 0; w2 < 8; w2++) t += red[l][w2];
        if (l == 3) t += bproj[0];
        tarr[l] = t;
    }
    for (int off = 1; off < NL; off <<= 1) {
        float v = (l >= off) ? s[l - off] : 0.0f;
        __syncthreads();
        s[l] += v;
        __syncthreads();
    }
    float mean = s[l] - 0.5f * d;
    means[b * NL + l] = mean;
    int base = b * NL;
    float dot;
    {
        const float4* dp = (const float4*)(dot8 + ((size_t)(base + l)) * 8);
        float4 a = dp[0], bb4 = dp[1];
        dot = ((a.x + a.y) + (a.z + a.w)) + ((bb4.x + bb4.y) + (bb4.z + bb4.w));
    }
    float dm1 = (l > 0)   ? df[base + l - 1] : 0.f;
    float d0  = df[base + l];
    float dp1 = (l < 511) ? df[base + l + 1] : 0.f;
    float lin = dot + tarr[3]
              + tarr[0] * dm1 + tarr[1] * d0 + tarr[2] * dp1;
    float r = (lin > 20.f) ? lin : log1pf(expf(lin));
    bool pad = (l >= lens[b]);
    if (pad) r = 1.0f;
    float sd = fmaxf(r, 0.001f);
    inv_std[base + l] = 1.0f / sd;
    Aarr[base + l] = pad ? -1e30f : (-logf(sd) - LOG_SQRT_2PI);
    if (!pad) {
        float fl = mean - ZWIN * sd - 1.0f;
        float fh = mean + ZWIN * sd + 1.0f;
        for (int tb = 0; tb < ntb; ++tb) {
            float t_lo = tb * 128.0f + 0.5f, t_hi = tb * 128.0f + 127.5f;
            if (fl <= t_hi && fh >= t_lo) {
                atomicMin(&slo[tb], l);
                atomicMax(&shi[tb], l);
            }
        }
    }
    __syncthreads();
    if (l < ntb) win[b * MAXTB + l] = make_int2(slo[l], shi[l]);
}

// ---------------- K3: banded GEMM; rn in-block; out_w rows split across e-blocks ----------------
__global__ __launch_bounds__(256) void k_gemm(const u16* __restrict__ XcT,
                                              const float* __restrict__ frames,
                                              const float* __restrict__ means,
                                              const float* __restrict__ inv_std,
                                              const float* __restrict__ Aarr,
                                              const int2* __restrict__ win,
                                              float* __restrict__ out,
                                              float* __restrict__ wout, int T) {
    __shared__ float4 sq[NL];
    __shared__ float fts[128];
    __shared__ float part[2][128];
    __shared__ float rvs[128];
    __shared__ u16 At[2][128][32];
    __shared__ u16 Bt[2][128][32];
    int b = blockIdx.z;
    int t0 = blockIdx.y * 128;
    int e0 = blockIdx.x * 128;
    int tid = threadIdx.x;
    int lane = tid & 63, wid = tid >> 6;
    int wm = wid >> 1, wn = wid & 1;
    const u16* Bb = XcT + (size_t)b * NE * NL;

    int2 w = win[b * MAXTB + blockIdx.y];
    int ks0 = 0, nst = 0;
    if (w.x <= w.y) { ks0 = w.x >> 5; nst = (w.y >> 5) - ks0 + 1; }
    int bl0 = ks0 * 32, bl1 = (ks0 + nst) * 32;

    // band-restricted stats load
    for (int i = bl0 + tid; i < bl1; i += 256)
        sq[i] = make_float4(means[b * NL + i], inv_std[b * NL + i], Aarr[b * NL + i], 0.f);
    if (tid < 128) fts[tid] = (t0 + tid < T) ? frames[t0 + tid] : -1e9f;

    __syncthreads();  // sq, fts ready

    // --- per-t normalizer: 2 threads per t sum the band ---
    if (nst > 0) {
        int tr = tid & 127, h = tid >> 7;
        float ftr = fts[tr];
        float ssum = 0.f;
        for (int l = w.x + h; l <= w.y; l += 2) {
            float4 q = sq[l];
            float z = (ftr - q.x) * q.y;
            ssum += __expf(fmaf(z, -0.5f * z, q.z));
        }
        part[h][tr] = ssum;
    }
    __syncthreads();
    if (tid < 128) rvs[tid] = 1.0f / (part[0][tid] + part[1][tid] + 1e-20f);
    __syncthreads();

    int ta = tid >> 1;        // A-row (t offset) this thread fills
    int ha = (tid & 1) * 16;  // which 16-col half
    float ft = fts[ta];
    float rv = rvs[ta];

    int srow = wid * 32 + (lane >> 2);
    int skc = (lane & 3) * 8;

    f32x4 acc[4][4];
    #pragma unroll
    for (int m = 0; m < 4; m++)
        #pragma unroll
        for (int n = 0; n < 4; n++)
            #pragma unroll
            for (int k = 0; k < 4; k++) acc[m][n][k] = 0.0f;

    auto stage = [&](int buf, int ks) {
        int l0 = ks * 32;
        const u16* gb = Bb + (size_t)(e0 + srow) * NL + l0 + skc;
        gload_lds16(gb, &Bt[buf][wid * 32][0]);
        gload_lds16(gb + 16 * NL, &Bt[buf][wid * 32 + 16][0]);
        u32 pk[8];
        #pragma unroll
        for (int jj = 0; jj < 8; ++jj) {
            float4 q0 = sq[l0 + ha + jj * 2];
            float4 q1 = sq[l0 + ha + jj * 2 + 1];
            float z0 = (ft - q0.x) * q0.y;
            float p0 = __expf(fmaf(z0, -0.5f * z0, q0.z)) * rv;
            float z1 = (ft - q1.x) * q1.y;
            float p1 = __expf(fmaf(z1, -0.5f * z1, q1.z)) * rv;
            pk[jj] = (u32)f2bf(p0) | ((u32)f2bf(p1) << 16);
        }
        *(uint4*)&At[buf][ta][ha]     = make_uint4(pk[0], pk[1], pk[2], pk[3]);
        *(uint4*)&At[buf][ta][ha + 8] = make_uint4(pk[4], pk[5], pk[6], pk[7]);
    };

    int fr = lane & 15, fk = (lane >> 4) * 8;
    if (nst > 0) {
        stage(0, ks0);
        for (int s = 0; s < nst; ++s) {
            __syncthreads();  // buf[s&1] (ds_writes + gload_lds) visible
            if (s + 1 < nst) stage((s + 1) & 1, ks0 + s + 1);
            int buf = s & 1;
            short8 a[4], bb[4];
            #pragma unroll
            for (int m = 0; m < 4; m++)
                a[m] = *(const short8*)&At[buf][wm * 64 + m * 16 + fr][fk];
            #pragma unroll
            for (int n = 0; n < 4; n++)
                bb[n] = *(const short8*)&Bt[buf][wn * 64 + n * 16 + fr][fk];
            #pragma unroll
            for (int m = 0; m < 4; m++)
                #pragma unroll
                for (int n = 0; n < 4; n++)
                    acc[m][n] = __builtin_amdgcn_mfma_f32_16x16x32_bf16(a[m], bb[n], acc[m][n], 0, 0, 0);
        }
    }

    // --- C-write ---
    int r4 = (lane >> 4) * 4;
    #pragma unroll
    for (int m = 0; m < 4; m++) {
        int tb2 = t0 + wm * 64 + m * 16 + r4;
        #pragma unroll
        for (int j = 0; j < 4; j++) {
            int t = tb2 + j;
            if (t < T) {
                float* orow = out + ((size_t)b * T + t) * NE + e0 + wn * 64 + (lane & 15);
                #pragma unroll
                for (int n = 0; n < 4; n++) orow[n * 16] = acc[m][n][j];
            }
        }
    }

    // --- out_w epilogue: this e-block writes rows [e0, e0+128), lane <-> t coalesced ---
    if (t0 < T) {
        int tcnt = T - t0; if (tcnt > 128) tcnt = 128;
        int rbeg = e0, rend = e0 + 128;
        int ib0 = bl0 > rbeg ? bl0 : rbeg;
        int ib1 = bl1 < rend ? bl1 : rend;
        int t4 = (tid & 31) * 4, rsub = tid >> 5;     // 8 rows per pass
        bool t4full = (t4 + 4 <= tcnt);
        float4 z4 = make_float4(0.f, 0.f, 0.f, 0.f);
        auto zfill = [&](int r0, int r1) {
            for (int l = r0 + rsub; l < r1; l += 8) {
                float* d = wout + ((size_t)b * NL + l) * T + t0 + t4;
                if (t4full) *(float4*)d = z4;
                else { for (int u = 0; u < 4 && t4 + u < tcnt; ++u) d[u] = 0.f; }
            }
        };
        if (ib0 >= ib1) {
            zfill(rbeg, rend);
        } else {
            zfill(rbeg, ib0);
            zfill(ib1, rend);
            int tt = tid & 127, half = tid >> 7;
            if (tt < tcnt) {
                float ftl = fts[tt], rvl = rvs[tt];
                float* dstc = wout + (size_t)b * NL * T + t0 + tt;
                for (int l = ib0 + half; l < ib1; l += 2) {
                    float4 q = sq[l];
                    float z = (ftl - q.x) * q.y;
                    dstc[(size_t)l * T] = __expf(fmaf(z, -0.5f * z, q.z)) * rvl;
                }
            }
        }
    }
}

extern "C" void kernel_launch(void* const* d_in, const int* in_sizes, int n_in,
                              void* d_out, int out_size, void* d_ws, size_t ws_size,
                              hipStream_t stream) {
    const float* x      = (const float*)d_in[0];
    const float* df     = (const float*)d_in[1];
    const int*   dint   = (const int*)d_in[2];
    const float* en     = (const float*)d_in[3];
    const float* pt     = (const float*)d_in[4];
    const int*   lens   = (const int*)d_in[5];
    const float* frames = (const float*)d_in[6];
    const float* wd     = (const float*)d_in[7];
    const float* bd     = (const float*)d_in[8];
    const float* wn     = (const float*)d_in[9];
    const float* bn     = (const float*)d_in[10];
    const float* wq     = (const float*)d_in[11];
    const float* bq     = (const float*)d_in[12];
    const float* wproj  = (const float*)d_in[13];
    const float* bproj  = (const float*)d_in[14];

    int T = in_sizes[6];
    int ntb = (T + 127) / 128;   // <= 32

    char* ws = (char*)d_ws;
    float* means   = (float*)(ws);             // B*L
    float* inv_std = (float*)(ws + 32768);     // B*L
    float* Aarr    = (float*)(ws + 65536);     // B*L
    float* dot8    = (float*)(ws + 98304);     // B*L*8 = 256 KB
    int2*  win     = (int2*)(ws + 360448);     // B*MAXTB
    u16*   XcT     = (u16*)(ws + 364544);      // B*E*L bf16 = 8.39 MB

    float* out_up = (float*)d_out;                 // (B,T,E)
    float* out_w  = out_up + (size_t)NB * T * NE;  // (B,L,T)

    k_xc<<<dim3(8, 8, NB), dim3(256), 0, stream>>>(x, en, pt, wn, bn, wq, bq, wproj,
                                                   XcT, dot8);
    k_pre<<<dim3(NB), dim3(512), 0, stream>>>(dint, df, lens, wproj, wd, bd, bproj,
                                              dot8, means, inv_std, Aarr, win, ntb);
    k_gemm<<<dim3(4, ntb, NB), dim3(256), 0, stream>>>(XcT, frames, means, inv_std,
                                                       Aarr, win, out_up, out_w, T);
}